// Round 10
// baseline (375.850 us; speedup 1.0000x reference)
//
#include <hip/hip_runtime.h>
#include <hip/hip_bf16.h>

typedef __attribute__((ext_vector_type(8))) __bf16 bf16x8;
typedef __attribute__((ext_vector_type(4))) __bf16 bf16x4;
typedef __attribute__((ext_vector_type(8))) unsigned short us8;
typedef __attribute__((ext_vector_type(4))) float f32x4;
typedef long long ll;

#define GLD(gp, lp) __builtin_amdgcn_global_load_lds( \
    (const __attribute__((address_space(1))) void*)(gp), \
    (__attribute__((address_space(3))) void*)(lp), 16, 0, 0)

#define SBAR()  asm volatile("s_barrier" ::: "memory")
#define VMCNT4  asm volatile("s_waitcnt vmcnt(4)" ::: "memory")
#define VMCNT0  asm volatile("s_waitcnt vmcnt(0)" ::: "memory")
#define SCHED0() __builtin_amdgcn_sched_barrier(0)

// ---------------------------------------------------------------------------
// 256x256-tile 8-phase GEMM (round-4 K-loop structure, unchanged).
// ROUND-10: MFMA operands SWAPPED (mfma(bB, bA)) so each lane's 4 acc regs
// span 4 consecutive C-COLUMNS of one C-row -> wide epilogue stores
// (32x 8B/16B instead of 128x 2B/4B; epilogue was store-issue-bound).
// New C mapping: row = wrm*128 + fi*16 + fr ; col = wcn*64 + j*16 + fq*4 + reg.
// OP 0: proj C=bf16 (+bias)
// OP 1: scores C=bf16 exp(v/32, masked; skip tiles); fused col-sums -> part
// OP 2: PV   C=fp32 (K truncated to row0+256 when masked)
// ---------------------------------------------------------------------------
template<int OP>
__global__ __launch_bounds__(512) void gemm8(
    const __bf16* __restrict__ A, const __bf16* __restrict__ B,
    void* __restrict__ Cp, const float* __restrict__ bias,
    const int* __restrict__ maskp, float* __restrict__ part,
    int K, int lda, int ldb, int ldc,
    ll batchA, ll batchB, ll batchC)
{
    __shared__ __bf16 LA[2][256][64];
    __shared__ __bf16 LB[2][256][64];

    const int bx = blockIdx.x, by = blockIdx.y, bz = blockIdx.z;
    const int t    = threadIdx.x;
    const int w    = t >> 6, lane = t & 63;
    const int wrm  = w >> 2, wcn  = w & 3;
    const int fr   = lane & 15, fq = lane >> 4;
    const int row0 = bx * 256;
    const int col0 = by * 256;
    const int msk  = (OP >= 1) ? maskp[0] : 0;

    // scores: fully-masked tile -> zeros (E and part), skip compute
    if (OP == 1 && msk && by > bx) {
        __bf16* C = (__bf16*)Cp + (ll)bz * batchC;
        bf16x8 z = {};
        #pragma unroll 4
        for (int pass = 0; pass < 16; ++pass) {
            int r = pass * 16 + (t >> 5);
            *(bf16x8*)&C[(ll)(row0 + r) * ldc + col0 + (t & 31) * 8] = z;
        }
        if (part && t < 256) part[((ll)bx * 8 + bz) * 2048 + col0 + t] = 0.f;
        return;
    }

    int NT = K / 64;
    if (OP == 2 && msk) NT = (row0 + 256) / 64;
    const int NI = NT / 2;

    const __bf16* Ab = A + (ll)bz * batchA;
    const __bf16* Bb = B + (ll)bz * batchB;

    const int srow = lane >> 3;
    const int cg   = (lane & 7) ^ srow;          // pre-swizzled source granule

    auto stageA = [&](int kt, int h, int slot) {
        #pragma unroll
        for (int is = 0; is < 2; ++is)
            GLD(Ab + (ll)(row0 + h*128 + is*64 + w*8 + srow) * lda + kt*64 + cg*8,
                &LA[slot][h*128 + is*64 + w*8][0]);
    };
    auto stageB = [&](int kt, int h, int slot) {
        #pragma unroll
        for (int is = 0; is < 2; ++is)
            GLD(Bb + (ll)(col0 + h*128 + is*64 + w*8 + srow) * ldb + kt*64 + cg*8,
                &LB[slot][h*128 + is*64 + w*8][0]);
    };
    auto rdA = [&](int slot, int row, int g) -> bf16x8 {
        return *(const bf16x8*)&LA[slot][row][(g ^ (row & 7)) << 3];
    };
    auto rdB = [&](int slot, int row, int g) -> bf16x8 {
        return *(const bf16x8*)&LB[slot][row][(g ^ (row & 7)) << 3];
    };

    f32x4  acc[8][4] = {};
    bf16x8 bB[4][2];

    // prologue: K-tile0 (A+B) -> slot0, B of K-tile1 -> slot1
    stageA(0, 0, 0); stageA(0, 1, 0);
    stageB(0, 0, 0); stageB(0, 1, 0);
    stageB(1, 0, 1); stageB(1, 1, 1);
    VMCNT4;
    SBAR();

#define PHASE(SLOT, Q, STG, VMC) \
  { \
    if (Q == 0) { \
      _Pragma("unroll") for (int j = 0; j < 4; ++j) \
      _Pragma("unroll") for (int ks = 0; ks < 2; ++ks) \
        bB[j][ks] = rdB(SLOT, wcn*64 + j*16 + fr, ks*4 + fq); \
    } \
    bf16x8 bA[2][2]; \
    _Pragma("unroll") for (int fi = 0; fi < 2; ++fi) \
    _Pragma("unroll") for (int ks = 0; ks < 2; ++ks) \
      bA[fi][ks] = rdA(SLOT, wrm*128 + (Q*2+fi)*16 + fr, ks*4 + fq); \
    STG; \
    VMC; \
    SBAR(); SCHED0(); \
    __builtin_amdgcn_s_setprio(1); \
    _Pragma("unroll") for (int fi = 0; fi < 2; ++fi) \
    _Pragma("unroll") for (int j = 0; j < 4; ++j) \
    _Pragma("unroll") for (int ks = 0; ks < 2; ++ks) \
      acc[Q*2+fi][j] = __builtin_amdgcn_mfma_f32_16x16x32_bf16( \
          bB[j][ks], bA[fi][ks], acc[Q*2+fi][j], 0, 0, 0); \
    __builtin_amdgcn_s_setprio(0); \
    SCHED0(); SBAR(); \
  }

    for (int i = 0; i < NI; ++i) {
        const bool nl = (i < NI - 1);
        const int k1 = 2*i + 1, k2 = 2*i + 2, k3 = 2*i + 3;
        PHASE(0, 0, stageA(k1, 0, 1), );
        PHASE(0, 1, stageA(k1, 1, 1), );
        PHASE(0, 2, if (nl) stageB(k2, 0, 0), );
        PHASE(0, 3, if (nl) stageB(k2, 1, 0), if (nl) { VMCNT4; } else { VMCNT0; });
        PHASE(1, 0, if (nl) stageA(k2, 0, 0), );
        PHASE(1, 1, if (nl) stageA(k2, 1, 0), );
        PHASE(1, 2, if (nl) stageB(k3, 0, 1), );
        PHASE(1, 3, if (nl) stageB(k3, 1, 1), if (nl) { VMCNT4; });
    }
#undef PHASE

    // ---- epilogue: row = wrm*128+fi*16+fr ; cols = wcn*64+j*16+fq*4+0..3 ----
    const ll coff = (ll)bz * batchC;
    if (OP == 0) {
        #pragma unroll
        for (int fi = 0; fi < 8; ++fi) {
            const int row = row0 + wrm*128 + fi*16 + fr;
            __bf16* crow = (__bf16*)Cp + coff + (ll)row*ldc + col0 + wcn*64 + fq*4;
            #pragma unroll
            for (int j = 0; j < 4; ++j) {
                f32x4 v = acc[fi][j];
                f32x4 bv = *(const f32x4*)&bias[col0 + wcn*64 + j*16 + fq*4];
                bf16x4 h;
                #pragma unroll
                for (int r = 0; r < 4; ++r) h[r] = (__bf16)(v[r] + bv[r]);
                *(bf16x4*)(crow + j*16) = h;
            }
        }
    } else if (OP == 1) {
        float s16[4][4];
        #pragma unroll
        for (int j = 0; j < 4; ++j)
        #pragma unroll
        for (int r = 0; r < 4; ++r) s16[j][r] = 0.f;

        #pragma unroll
        for (int fi = 0; fi < 8; ++fi) {
            const int row = row0 + wrm*128 + fi*16 + fr;
            __bf16* crow = (__bf16*)Cp + coff + (ll)row*ldc + col0 + wcn*64 + fq*4;
            #pragma unroll
            for (int j = 0; j < 4; ++j) {
                bf16x4 h;
                #pragma unroll
                for (int r = 0; r < 4; ++r) {
                    const int col = col0 + wcn*64 + j*16 + fq*4 + r;
                    float e = (msk && col > row) ? 0.f
                                                 : __expf(acc[fi][j][r] * 0.03125f);
                    __bf16 eb = (__bf16)e;
                    h[r] = eb;
                    s16[j][r] += (float)eb;     // sum what was stored
                }
                *(bf16x4*)(crow + j*16) = h;
            }
        }
        if (part != nullptr) {
            // reduce over the 16 fr-lanes (each fq-group shares its 16 cols)
            #pragma unroll
            for (int j = 0; j < 4; ++j)
            #pragma unroll
            for (int r = 0; r < 4; ++r) {
                float v = s16[j][r];
                v += __shfl_xor(v, 1);
                v += __shfl_xor(v, 2);
                v += __shfl_xor(v, 4);
                v += __shfl_xor(v, 8);
                s16[j][r] = v;
            }
            float* red = (float*)&LA[0][0][0];   // 512 floats, LDS reuse
            __syncthreads();
            if (fr == 0) {
                #pragma unroll
                for (int j = 0; j < 4; ++j)
                #pragma unroll
                for (int r = 0; r < 4; ++r)
                    red[wrm*256 + wcn*64 + j*16 + fq*4 + r] = s16[j][r];
            }
            __syncthreads();
            if (t < 256)
                part[((ll)bx * 8 + bz) * 2048 + col0 + t] = red[t] + red[256 + t];
        }
    } else {
        #pragma unroll
        for (int fi = 0; fi < 8; ++fi) {
            const int row = row0 + wrm*128 + fi*16 + fr;
            float* crow = (float*)Cp + coff + (ll)row*ldc + col0 + wcn*64 + fq*4;
            #pragma unroll
            for (int j = 0; j < 4; ++j)
                *(f32x4*)(crow + j*16) = acc[fi][j];
        }
    }
}

// ---------------------------------------------------------------------------
__global__ __launch_bounds__(256) void cvt_k(const float* __restrict__ in,
                                             __bf16* __restrict__ out, int n8)
{
    const int i = blockIdx.x * 256 + threadIdx.x;
    if (i >= n8) return;
    const f32x4* p = (const f32x4*)(in + (ll)i * 8);
    f32x4 a = p[0], b = p[1];
    bf16x8 h;
    #pragma unroll
    for (int j = 0; j < 4; ++j) { h[j] = (__bf16)a[j]; h[j + 4] = (__bf16)b[j]; }
    *(bf16x8*)(out + (ll)i * 8) = h;
}

__global__ __launch_bounds__(256) void cvtb_k(const float* __restrict__ q,
                                              const float* __restrict__ k,
                                              const float* __restrict__ v,
                                              float* __restrict__ bb)
{
    const int i = blockIdx.x * 256 + threadIdx.x;
    bb[i] = (i < 1024) ? q[i] : (i < 2048) ? k[i - 1024] : v[i - 2048];
}

// ---------------------------------------------------------------------------
// reduce part over lc -> inv[b][m] = 1/colsum
// ---------------------------------------------------------------------------
__global__ __launch_bounds__(256) void rsum_k(const float* __restrict__ part,
                                              float* __restrict__ inv)
{
    const int idx = blockIdx.x * 256 + threadIdx.x;   // 0..16383
    const int b = idx >> 11, m = idx & 2047;
    float s = 0.f;
    #pragma unroll
    for (int lc = 0; lc < 8; ++lc) s += part[((ll)lc * 8 + b) * 2048 + m];
    inv[idx] = 1.0f / s;
}

// ---------------------------------------------------------------------------
// V' transpose with folded inv: vt[b][d][m] = V[b][m][d] * inv[b][m]
// ---------------------------------------------------------------------------
__global__ __launch_bounds__(256) void vtp_k(const __bf16* __restrict__ qkv,
                                             const float* __restrict__ inv,
                                             __bf16* __restrict__ vt)
{
    __shared__ __bf16 tile[64][72];
    const int t  = threadIdx.x;
    const int m0 = blockIdx.x * 64;
    const int k0 = blockIdx.y * 64;
    const int b  = blockIdx.z;

    const __bf16* V = qkv + (ll)b * 2048 * 3072 + 2048;
    #pragma unroll
    for (int h = 0; h < 2; ++h) {
        int r = (t >> 3) + h * 32;
        int c = (t & 7) * 8;
        int m = m0 + r;
        const float iv = inv[b * 2048 + m];
        bf16x8 v = *(const bf16x8*)&V[(ll)m * 3072 + k0 + c];
        bf16x8 o;
        #pragma unroll
        for (int j = 0; j < 8; ++j) o[j] = (__bf16)((float)v[j] * iv);
        *(bf16x8*)&tile[r][c] = o;
    }
    __syncthreads();
    __bf16* O = vt + (ll)b * 1024 * 2048;
    #pragma unroll
    for (int h = 0; h < 2; ++h) {
        int k = (t >> 3) + h * 32;
        int m = (t & 7) * 8;
        bf16x8 o;
        #pragma unroll
        for (int j = 0; j < 8; ++j) o[j] = tile[m + j][k];
        *(bf16x8*)&O[(ll)(k0 + k) * 2048 + m0 + m] = o;
    }
}

// plain V transpose (fallback path)
__global__ __launch_bounds__(256) void vt_k(const unsigned short* __restrict__ qkv,
                                            unsigned short* __restrict__ vt)
{
    __shared__ unsigned short tile[64][72];
    const int t  = threadIdx.x;
    const int m0 = blockIdx.x * 64;
    const int k0 = blockIdx.y * 64;
    const int b  = blockIdx.z;

    const unsigned short* V = qkv + (ll)b * 2048 * 3072 + 2048;
    #pragma unroll
    for (int h = 0; h < 2; ++h) {
        int r = (t >> 3) + h * 32;
        int c = (t & 7) * 8;
        us8 v = *(const us8*)&V[(ll)(m0 + r) * 3072 + k0 + c];
        *(us8*)&tile[r][c] = v;
    }
    __syncthreads();
    unsigned short* O = vt + (ll)b * 1024 * 2048;
    #pragma unroll
    for (int h = 0; h < 2; ++h) {
        int k = (t >> 3) + h * 32;
        int m = (t & 7) * 8;
        us8 o;
        #pragma unroll
        for (int j = 0; j < 8; ++j) o[j] = tile[m + j][k];
        *(us8*)&O[(ll)(k0 + k) * 2048 + m0 + m] = o;
    }
}

// ---------------------------------------------------------------------------
// norm2 (fused path): attn fp32 = E * inv   (the required attention output)
// ---------------------------------------------------------------------------
__global__ __launch_bounds__(256) void norm2_k(const __bf16* __restrict__ E,
                                               const float* __restrict__ inv,
                                               float* __restrict__ attn)
{
    const int lc = blockIdx.x, mc = blockIdx.y, b = blockIdx.z;
    const int m  = mc * 256 + threadIdx.x;
    const float iv = inv[b * 2048 + m];
    const __bf16* p = E + (ll)b * 2048 * 2048 + (ll)(lc * 256) * 2048 + m;
    float* qo = attn + (ll)b * 2048 * 2048 + (ll)(lc * 256) * 2048 + m;
    #pragma unroll 4
    for (int l = 0; l < 256; ++l)
        qo[(ll)l * 2048] = (float)p[(ll)l * 2048] * iv;
}

// fallback-path aux (round-4 proven versions)
__global__ __launch_bounds__(256) void colsum_k(const __bf16* __restrict__ E,
                                                float* __restrict__ part)
{
    const int lc = blockIdx.x, mc = blockIdx.y, b = blockIdx.z;
    const int m  = mc * 256 + threadIdx.x;
    const __bf16* p = E + (ll)b * 2048 * 2048 + (ll)(lc * 256) * 2048 + m;
    float s = 0.f;
    #pragma unroll 4
    for (int l = 0; l < 256; ++l) s += (float)p[(ll)l * 2048];
    part[((ll)lc * 8 + b) * 2048 + m] = s;
}

__global__ __launch_bounds__(256) void norm_k(const __bf16* __restrict__ E,
                                              const float* __restrict__ part,
                                              float* __restrict__ attn,
                                              __bf16* __restrict__ attn_bf)
{
    const int lc = blockIdx.x, mc = blockIdx.y, b = blockIdx.z;
    const int m  = mc * 256 + threadIdx.x;
    float s = 0.f;
    #pragma unroll
    for (int j = 0; j < 8; ++j) s += part[((ll)j * 8 + b) * 2048 + m];
    const float iv = 1.0f / s;
    const __bf16* p = E + (ll)b * 2048 * 2048 + (ll)(lc * 256) * 2048 + m;
    float*  qo = attn    + (ll)b * 2048 * 2048 + (ll)(lc * 256) * 2048 + m;
    __bf16* ro = attn_bf + (ll)b * 2048 * 2048 + (ll)(lc * 256) * 2048 + m;
    #pragma unroll 4
    for (int l = 0; l < 256; ++l) {
        float a = (float)p[(ll)l * 2048] * iv;
        qo[(ll)l * 2048] = a;
        ro[(ll)l * 2048] = (__bf16)a;
    }
}

// ---------------------------------------------------------------------------
extern "C" void kernel_launch(void* const* d_in, const int* in_sizes, int n_in,
                              void* d_out, int out_size, void* d_ws, size_t ws_size,
                              hipStream_t stream)
{
    const float* X   = (const float*)d_in[0];
    const float* Wq  = (const float*)d_in[1];
    const float* bq  = (const float*)d_in[2];
    const float* Wk  = (const float*)d_in[3];
    const float* bk  = (const float*)d_in[4];
    const float* Wv  = (const float*)d_in[5];
    const float* bv  = (const float*)d_in[6];
    const int*   msk = (const int*)d_in[7];

    float* out  = (float*)d_out;                  // (8,2048,1024) fp32
    float* attn = out + (ll)8 * 2048 * 1024;      // (8,2048,2048) fp32

    __bf16* Xb = (__bf16*)attn;                   // staging in attn region
    __bf16* Wb = Xb + (ll)16384 * 1024;
    float*  bb = (float*)(Wb + (ll)3072 * 1024);

    __bf16* qkv = (__bf16*)d_ws;                  // 96 MiB
    __bf16* vt  = qkv + (ll)16384 * 3072;         // 32 MiB

    // 0) bf16 conversions (both paths)
    cvt_k<<<dim3(8192), 256, 0, stream>>>(X, Xb, 16384 * 1024 / 8);
    cvt_k<<<dim3(512),  256, 0, stream>>>(Wq, Wb,               1024 * 1024 / 8);
    cvt_k<<<dim3(512),  256, 0, stream>>>(Wk, Wb + 1024 * 1024, 1024 * 1024 / 8);
    cvt_k<<<dim3(512),  256, 0, stream>>>(Wv, Wb + 2048 * 1024, 1024 * 1024 / 8);
    cvtb_k<<<dim3(12),  256, 0, stream>>>(bq, bk, bv, bb);

    // 1) QKV projection (both paths)
    gemm8<0><<<dim3(64, 12, 1), 512, 0, stream>>>(
        Xb, Wb, qkv, bb, msk, nullptr,
        1024, 1024, 1024, 3072, 0LL, 0LL, 0LL);

    const size_t need_fused =
        (size_t)(16384ll*3072 + 8ll*1024*2048 + 8ll*2048*2048) * 2   // qkv+vt+E
        + (size_t)(8*8*2048 + 8*2048) * 4;                           // part+inv

    if (ws_size >= need_fused) {
        // ---------------- fused path: E in ws, inv folded into V^T ---------
        __bf16* E   = vt + (ll)8 * 1024 * 2048;           // 64 MiB
        float*  prt = (float*)(E + (ll)8 * 2048 * 2048);  // 8*8*2048
        float*  inv = prt + 8 * 8 * 2048;                 // 8*2048

        // 2) E = exp(QK^T/32, masked) -> ws; fused column partial sums
        gemm8<1><<<dim3(8, 8, 8), 512, 0, stream>>>(
            qkv, qkv + 1024, E, nullptr, msk, prt,
            1024, 3072, 3072, 2048,
            (ll)2048 * 3072, (ll)2048 * 3072, (ll)2048 * 2048);

        // 3) inv = 1/colsum
        rsum_k<<<dim3(64), 256, 0, stream>>>(prt, inv);

        // 4) vt = (V * inv)^T   (V from qkv, still live)
        vtp_k<<<dim3(32, 16, 8), 256, 0, stream>>>(qkv, inv, vt);

        // 5) attention output fp32 = E * inv  (Xb/Wb staging dead now)
        norm2_k<<<dim3(8, 8, 8), 256, 0, stream>>>(E, inv, attn);

        // 6) out = E @ vt^T  (A=E in ws: no aliasing with d_out)
        gemm8<2><<<dim3(8, 4, 8), 512, 0, stream>>>(
            E, vt, out, nullptr, msk, nullptr,
            2048, 2048, 2048, 1024,
            (ll)2048 * 2048, (ll)1024 * 2048, (ll)2048 * 1024);
    } else {
        // ---------------- fallback: round-4 proven pipeline ----------------
        __bf16* E   = (__bf16*)d_out;                     // E in out region
        float*  prt = (float*)(vt + (ll)8 * 1024 * 2048);
        __bf16* attn_bf = qkv;                            // reuse qkv later

        vt_k<<<dim3(32, 16, 8), 256, 0, stream>>>((const unsigned short*)qkv,
                                                  (unsigned short*)vt);

        gemm8<1><<<dim3(8, 8, 8), 512, 0, stream>>>(
            qkv, qkv + 1024, E, nullptr, msk, nullptr,
            1024, 3072, 3072, 2048,
            (ll)2048 * 3072, (ll)2048 * 3072, (ll)2048 * 2048);

        colsum_k<<<dim3(8, 8, 8), 256, 0, stream>>>(E, prt);
        norm_k<<<dim3(8, 8, 8), 256, 0, stream>>>(E, prt, attn, attn_bf);

        gemm8<2><<<dim3(8, 4, 8), 512, 0, stream>>>(
            attn_bf, vt, out, nullptr, msk, nullptr,
            2048, 2048, 2048, 1024,
            (ll)2048 * 2048, (ll)1024 * 2048, (ll)2048 * 1024);
    }
}

// Round 11
// 335.919 us; speedup vs baseline: 1.1189x; 1.1189x over previous
//
#include <hip/hip_runtime.h>
#include <hip/hip_bf16.h>

typedef __attribute__((ext_vector_type(8))) __bf16 bf16x8;
typedef __attribute__((ext_vector_type(8))) unsigned short us8;
typedef __attribute__((ext_vector_type(4))) float f32x4;
typedef long long ll;

#define GLD(gp, lp) __builtin_amdgcn_global_load_lds( \
    (const __attribute__((address_space(1))) void*)(gp), \
    (__attribute__((address_space(3))) void*)(lp), 16, 0, 0)

#define SBAR()  asm volatile("s_barrier" ::: "memory")
#define VMCNT4  asm volatile("s_waitcnt vmcnt(4)" ::: "memory")
#define VMCNT0  asm volatile("s_waitcnt vmcnt(0)" ::: "memory")
#define SCHED0() __builtin_amdgcn_sched_barrier(0)

// ---------------------------------------------------------------------------
// 256x256-tile 8-phase GEMM (round-9 structure verbatim — best measured).
// OP 0: proj C=bf16 (+bias)
// OP 1: scores C=bf16 exp(v/32, masked; skip tiles); fused col-sums -> part
// OP 2: PV (fallback path only)
// ---------------------------------------------------------------------------
template<int OP>
__global__ __launch_bounds__(512) void gemm8(
    const __bf16* __restrict__ A, const __bf16* __restrict__ B,
    void* __restrict__ Cp, const float* __restrict__ bias,
    const int* __restrict__ maskp, float* __restrict__ part,
    int K, int lda, int ldb, int ldc,
    ll batchA, ll batchB, ll batchC)
{
    __shared__ __bf16 LA[2][256][64];
    __shared__ __bf16 LB[2][256][64];

    const int bx = blockIdx.x, by = blockIdx.y, bz = blockIdx.z;
    const int t    = threadIdx.x;
    const int w    = t >> 6, lane = t & 63;
    const int wrm  = w >> 2, wcn  = w & 3;
    const int fr   = lane & 15, fq = lane >> 4;
    const int row0 = bx * 256;
    const int col0 = by * 256;
    const int msk  = (OP >= 1) ? maskp[0] : 0;

    if (OP == 1 && msk && by > bx) {
        __bf16* C = (__bf16*)Cp + (ll)bz * batchC;
        bf16x8 z = {};
        #pragma unroll 4
        for (int pass = 0; pass < 16; ++pass) {
            int r = pass * 16 + (t >> 5);
            *(bf16x8*)&C[(ll)(row0 + r) * ldc + col0 + (t & 31) * 8] = z;
        }
        if (part && t < 256) part[((ll)bx * 8 + bz) * 2048 + col0 + t] = 0.f;
        return;
    }

    int NT = K / 64;
    if (OP == 2 && msk) NT = (row0 + 256) / 64;
    const int NI = NT / 2;

    const __bf16* Ab = A + (ll)bz * batchA;
    const __bf16* Bb = B + (ll)bz * batchB;

    const int srow = lane >> 3;
    const int cg   = (lane & 7) ^ srow;

    auto stageA = [&](int kt, int h, int slot) {
        #pragma unroll
        for (int is = 0; is < 2; ++is)
            GLD(Ab + (ll)(row0 + h*128 + is*64 + w*8 + srow) * lda + kt*64 + cg*8,
                &LA[slot][h*128 + is*64 + w*8][0]);
    };
    auto stageB = [&](int kt, int h, int slot) {
        #pragma unroll
        for (int is = 0; is < 2; ++is)
            GLD(Bb + (ll)(col0 + h*128 + is*64 + w*8 + srow) * ldb + kt*64 + cg*8,
                &LB[slot][h*128 + is*64 + w*8][0]);
    };
    auto rdA = [&](int slot, int row, int g) -> bf16x8 {
        return *(const bf16x8*)&LA[slot][row][(g ^ (row & 7)) << 3];
    };
    auto rdB = [&](int slot, int row, int g) -> bf16x8 {
        return *(const bf16x8*)&LB[slot][row][(g ^ (row & 7)) << 3];
    };

    f32x4  acc[8][4] = {};
    bf16x8 bB[4][2];

    stageA(0, 0, 0); stageA(0, 1, 0);
    stageB(0, 0, 0); stageB(0, 1, 0);
    stageB(1, 0, 1); stageB(1, 1, 1);
    VMCNT4;
    SBAR();

#define PHASE(SLOT, Q, STG, VMC) \
  { \
    if (Q == 0) { \
      _Pragma("unroll") for (int j = 0; j < 4; ++j) \
      _Pragma("unroll") for (int ks = 0; ks < 2; ++ks) \
        bB[j][ks] = rdB(SLOT, wcn*64 + j*16 + fr, ks*4 + fq); \
    } \
    bf16x8 bA[2][2]; \
    _Pragma("unroll") for (int fi = 0; fi < 2; ++fi) \
    _Pragma("unroll") for (int ks = 0; ks < 2; ++ks) \
      bA[fi][ks] = rdA(SLOT, wrm*128 + (Q*2+fi)*16 + fr, ks*4 + fq); \
    STG; \
    VMC; \
    SBAR(); SCHED0(); \
    __builtin_amdgcn_s_setprio(1); \
    _Pragma("unroll") for (int fi = 0; fi < 2; ++fi) \
    _Pragma("unroll") for (int j = 0; j < 4; ++j) \
    _Pragma("unroll") for (int ks = 0; ks < 2; ++ks) \
      acc[Q*2+fi][j] = __builtin_amdgcn_mfma_f32_16x16x32_bf16( \
          bA[fi][ks], bB[j][ks], acc[Q*2+fi][j], 0, 0, 0); \
    __builtin_amdgcn_s_setprio(0); \
    SCHED0(); SBAR(); \
  }

    for (int i = 0; i < NI; ++i) {
        const bool nl = (i < NI - 1);
        const int k1 = 2*i + 1, k2 = 2*i + 2, k3 = 2*i + 3;
        PHASE(0, 0, stageA(k1, 0, 1), );
        PHASE(0, 1, stageA(k1, 1, 1), );
        PHASE(0, 2, if (nl) stageB(k2, 0, 0), );
        PHASE(0, 3, if (nl) stageB(k2, 1, 0), if (nl) { VMCNT4; } else { VMCNT0; });
        PHASE(1, 0, if (nl) stageA(k2, 0, 0), );
        PHASE(1, 1, if (nl) stageA(k2, 1, 0), );
        PHASE(1, 2, if (nl) stageB(k3, 0, 1), );
        PHASE(1, 3, if (nl) stageB(k3, 1, 1), if (nl) { VMCNT4; });
    }
#undef PHASE

    const ll coff = (ll)bz * batchC;
    float s4[4] = {0.f, 0.f, 0.f, 0.f};
    #pragma unroll
    for (int fi = 0; fi < 8; ++fi)
    #pragma unroll
    for (int j = 0; j < 4; ++j)
    #pragma unroll
    for (int r4 = 0; r4 < 4; ++r4) {
        const int row = row0 + wrm*128 + fi*16 + fq*4 + r4;
        const int col = col0 + wcn*64 + j*16 + fr;
        float v = acc[fi][j][r4];
        if (OP == 0) {
            v += bias[col];
            ((__bf16*)Cp)[coff + (ll)row * ldc + col] = (__bf16)v;
        } else if (OP == 1) {
            float e = (msk && col > row) ? 0.f : __expf(v * 0.03125f);
            __bf16 eb = (__bf16)e;
            ((__bf16*)Cp)[coff + (ll)row * ldc + col] = eb;
            s4[j] += (float)eb;
        } else {
            ((float*)Cp)[coff + (ll)row * ldc + col] = v;
        }
    }
    if (OP == 1 && part != nullptr) {
        float* red = (float*)&LA[0][0][0];
        __syncthreads();
        #pragma unroll
        for (int j = 0; j < 4; ++j)
            red[(wrm*4 + fq)*256 + wcn*64 + j*16 + fr] = s4[j];
        __syncthreads();
        if (t < 256) {
            float tot = 0.f;
            #pragma unroll
            for (int r = 0; r < 8; ++r) tot += red[r*256 + t];
            part[((ll)bx * 8 + bz) * 2048 + col0 + t] = tot;
        }
    }
}

// ---------------------------------------------------------------------------
// PV with BM=128 (acc[4][4], LDS 96KB), longest-first bx remap, and fused
// attention-output chunk write (attn = E*inv). Grid (16, 4, 8).
//   out[bz] rows [bxr*128,+128) x cols [by*256,+256)
//   attn[bz] rows [bxr*128,+128) x cols [by*512,+512)
// Ledger (steady state, tiles a=2i->s0, b=2i+1->s1):
//   p1(s0,Q0): stage A(b)->s1            p2(s0,Q1): stage B(a+2)->s0, VMCNT(4)
//   p3(s1,Q0): stage A(a+2)->s0          p4(s1,Q1): stage B(b+2)->s1, VMCNT(4)
// Invariant: after each VMCNT(4) the 4 in-flight are exactly the newest B.
// ---------------------------------------------------------------------------
__global__ __launch_bounds__(512) void pv128(
    const __bf16* __restrict__ E, const __bf16* __restrict__ VT,
    const float* __restrict__ inv, float* __restrict__ out,
    float* __restrict__ attn, const int* __restrict__ maskp)
{
    __shared__ __bf16 LA[2][128][64];
    __shared__ __bf16 LB[2][256][64];

    const int bxr = (int)gridDim.x - 1 - (int)blockIdx.x;  // longest first
    const int by = blockIdx.y, bz = blockIdx.z;
    const int t = threadIdx.x, w = t >> 6, lane = t & 63;
    const int wrm = w >> 2, wcn = w & 3;
    const int fr = lane & 15, fq = lane >> 4;
    const int row0 = bxr * 128, col0 = by * 256;
    const int msk = maskp[0];

    const int NT = msk ? (row0 + 128) / 64 : 32;
    const int NI = NT / 2;

    const __bf16* Ab = E  + (ll)bz * 2048 * 2048;
    const __bf16* Bb = VT + (ll)bz * 1024 * 2048;

    const int srow = lane >> 3;
    const int cg   = (lane & 7) ^ srow;

    auto stageA = [&](int kt, int slot) {
        #pragma unroll
        for (int is = 0; is < 2; ++is)
            GLD(Ab + (ll)(row0 + is*64 + w*8 + srow) * 2048 + kt*64 + cg*8,
                &LA[slot][is*64 + w*8][0]);
    };
    auto stageB = [&](int kt, int h, int slot) {
        #pragma unroll
        for (int is = 0; is < 2; ++is)
            GLD(Bb + (ll)(col0 + h*128 + is*64 + w*8 + srow) * 2048 + kt*64 + cg*8,
                &LB[slot][h*128 + is*64 + w*8][0]);
    };
    auto rdA = [&](int slot, int row, int g) -> bf16x8 {
        return *(const bf16x8*)&LA[slot][row][(g ^ (row & 7)) << 3];
    };
    auto rdB = [&](int slot, int row, int g) -> bf16x8 {
        return *(const bf16x8*)&LB[slot][row][(g ^ (row & 7)) << 3];
    };

    f32x4  acc[4][4] = {};
    bf16x8 bB[4][2];

    // prologue: A(0),B(0)->s0 ; B(1)->s1 ; drain A0+B0 (10-4=6 oldest)
    stageA(0, 0); stageB(0, 0, 0); stageB(0, 1, 0);
    stageB(1, 0, 1); stageB(1, 1, 1);
    VMCNT4;
    SBAR();

#define PHASEP(SLOT, Q, STG, VMC) \
  { \
    if (Q == 0) { \
      _Pragma("unroll") for (int j = 0; j < 4; ++j) \
      _Pragma("unroll") for (int ks = 0; ks < 2; ++ks) \
        bB[j][ks] = rdB(SLOT, wcn*64 + j*16 + fr, ks*4 + fq); \
    } \
    bf16x8 bA[2][2]; \
    _Pragma("unroll") for (int fi = 0; fi < 2; ++fi) \
    _Pragma("unroll") for (int ks = 0; ks < 2; ++ks) \
      bA[fi][ks] = rdA(SLOT, wrm*64 + (Q*2+fi)*16 + fr, ks*4 + fq); \
    STG; \
    VMC; \
    SBAR(); SCHED0(); \
    __builtin_amdgcn_s_setprio(1); \
    _Pragma("unroll") for (int fi = 0; fi < 2; ++fi) \
    _Pragma("unroll") for (int j = 0; j < 4; ++j) \
    _Pragma("unroll") for (int ks = 0; ks < 2; ++ks) \
      acc[Q*2+fi][j] = __builtin_amdgcn_mfma_f32_16x16x32_bf16( \
          bA[fi][ks], bB[j][ks], acc[Q*2+fi][j], 0, 0, 0); \
    __builtin_amdgcn_s_setprio(0); \
    SCHED0(); SBAR(); \
  }

    for (int i = 0; i < NI; ++i) {
        const bool nl = (i < NI - 1);
        const int kb = 2*i + 1, ka2 = 2*i + 2, kb2 = 2*i + 3;
        PHASEP(0, 0, stageA(kb, 1), );
        PHASEP(0, 1, if (nl) { stageB(ka2, 0, 0); stageB(ka2, 1, 0); },
                     if (nl) { VMCNT4; } else { VMCNT0; });
        PHASEP(1, 0, if (nl) stageA(ka2, 0), );
        PHASEP(1, 1, if (nl) { stageB(kb2, 0, 1); stageB(kb2, 1, 1); },
                     if (nl) { VMCNT4; });
    }
#undef PHASEP

    // out stores
    #pragma unroll
    for (int qf = 0; qf < 4; ++qf)
    #pragma unroll
    for (int j = 0; j < 4; ++j)
    #pragma unroll
    for (int r4 = 0; r4 < 4; ++r4) {
        const int row = row0 + wrm*64 + qf*16 + fq*4 + r4;
        const int col = col0 + wcn*64 + j*16 + fr;
        out[(ll)bz*2048*1024 + (ll)row*1024 + col] = acc[qf][j][r4];
    }

    // fused attention output: attn[rows row0..+128][cols by*512..+512) = E*inv
    {
        const int c0 = by * 512;
        const int ct = (t & 63) * 8;
        float iv[8];
        #pragma unroll
        for (int e = 0; e < 8; ++e) iv[e] = inv[bz*2048 + c0 + ct + e];
        const int r00 = t >> 6;             // 0..7
        #pragma unroll 2
        for (int ri = 0; ri < 16; ++ri) {
            const int row = row0 + ri*8 + r00;
            bf16x8 ev = *(const bf16x8*)&Ab[(ll)row*2048 + c0 + ct];
            f32x4 lo, hi;
            #pragma unroll
            for (int e = 0; e < 4; ++e) {
                lo[e] = (float)ev[e]     * iv[e];
                hi[e] = (float)ev[e + 4] * iv[e + 4];
            }
            float* ao = attn + (ll)bz*2048*2048 + (ll)row*2048 + c0 + ct;
            ((f32x4*)ao)[0] = lo;
            ((f32x4*)ao)[1] = hi;
        }
    }
}

// ---------------------------------------------------------------------------
__global__ __launch_bounds__(256) void cvt_k(const float* __restrict__ in,
                                             __bf16* __restrict__ out, int n8)
{
    const int i = blockIdx.x * 256 + threadIdx.x;
    if (i >= n8) return;
    const f32x4* p = (const f32x4*)(in + (ll)i * 8);
    f32x4 a = p[0], b = p[1];
    bf16x8 h;
    #pragma unroll
    for (int j = 0; j < 4; ++j) { h[j] = (__bf16)a[j]; h[j + 4] = (__bf16)b[j]; }
    *(bf16x8*)(out + (ll)i * 8) = h;
}

__global__ __launch_bounds__(256) void cvtb_k(const float* __restrict__ q,
                                              const float* __restrict__ k,
                                              const float* __restrict__ v,
                                              float* __restrict__ bb)
{
    const int i = blockIdx.x * 256 + threadIdx.x;
    bb[i] = (i < 1024) ? q[i] : (i < 2048) ? k[i - 1024] : v[i - 2048];
}

// ---------------------------------------------------------------------------
__global__ __launch_bounds__(256) void rsum_k(const float* __restrict__ part,
                                              float* __restrict__ inv)
{
    const int idx = blockIdx.x * 256 + threadIdx.x;
    const int b = idx >> 11, m = idx & 2047;
    float s = 0.f;
    #pragma unroll
    for (int lc = 0; lc < 8; ++lc) s += part[((ll)lc * 8 + b) * 2048 + m];
    inv[idx] = 1.0f / s;
}

// ---------------------------------------------------------------------------
__global__ __launch_bounds__(256) void vtp_k(const __bf16* __restrict__ qkv,
                                             const float* __restrict__ inv,
                                             __bf16* __restrict__ vt)
{
    __shared__ __bf16 tile[64][72];
    const int t  = threadIdx.x;
    const int m0 = blockIdx.x * 64;
    const int k0 = blockIdx.y * 64;
    const int b  = blockIdx.z;

    const __bf16* V = qkv + (ll)b * 2048 * 3072 + 2048;
    #pragma unroll
    for (int h = 0; h < 2; ++h) {
        int r = (t >> 3) + h * 32;
        int c = (t & 7) * 8;
        int m = m0 + r;
        const float iv = inv[b * 2048 + m];
        bf16x8 v = *(const bf16x8*)&V[(ll)m * 3072 + k0 + c];
        bf16x8 o;
        #pragma unroll
        for (int j = 0; j < 8; ++j) o[j] = (__bf16)((float)v[j] * iv);
        *(bf16x8*)&tile[r][c] = o;
    }
    __syncthreads();
    __bf16* O = vt + (ll)b * 1024 * 2048;
    #pragma unroll
    for (int h = 0; h < 2; ++h) {
        int k = (t >> 3) + h * 32;
        int m = (t & 7) * 8;
        bf16x8 o;
        #pragma unroll
        for (int j = 0; j < 8; ++j) o[j] = tile[m + j][k];
        *(bf16x8*)&O[(ll)(k0 + k) * 2048 + m0 + m] = o;
    }
}

// plain V transpose (fallback path)
__global__ __launch_bounds__(256) void vt_k(const unsigned short* __restrict__ qkv,
                                            unsigned short* __restrict__ vt)
{
    __shared__ unsigned short tile[64][72];
    const int t  = threadIdx.x;
    const int m0 = blockIdx.x * 64;
    const int k0 = blockIdx.y * 64;
    const int b  = blockIdx.z;

    const unsigned short* V = qkv + (ll)b * 2048 * 3072 + 2048;
    #pragma unroll
    for (int h = 0; h < 2; ++h) {
        int r = (t >> 3) + h * 32;
        int c = (t & 7) * 8;
        us8 v = *(const us8*)&V[(ll)(m0 + r) * 3072 + k0 + c];
        *(us8*)&tile[r][c] = v;
    }
    __syncthreads();
    unsigned short* O = vt + (ll)b * 1024 * 2048;
    #pragma unroll
    for (int h = 0; h < 2; ++h) {
        int k = (t >> 3) + h * 32;
        int m = (t & 7) * 8;
        us8 o;
        #pragma unroll
        for (int j = 0; j < 8; ++j) o[j] = tile[m + j][k];
        *(us8*)&O[(ll)(k0 + k) * 2048 + m0 + m] = o;
    }
}

// fallback-path aux
__global__ __launch_bounds__(256) void colsum_k(const __bf16* __restrict__ E,
                                                float* __restrict__ part)
{
    const int lc = blockIdx.x, mc = blockIdx.y, b = blockIdx.z;
    const int m  = mc * 256 + threadIdx.x;
    const __bf16* p = E + (ll)b * 2048 * 2048 + (ll)(lc * 256) * 2048 + m;
    float s = 0.f;
    #pragma unroll 4
    for (int l = 0; l < 256; ++l) s += (float)p[(ll)l * 2048];
    part[((ll)lc * 8 + b) * 2048 + m] = s;
}

__global__ __launch_bounds__(256) void norm_k(const __bf16* __restrict__ E,
                                              const float* __restrict__ part,
                                              float* __restrict__ attn,
                                              __bf16* __restrict__ attn_bf)
{
    const int lc = blockIdx.x, mc = blockIdx.y, b = blockIdx.z;
    const int m  = mc * 256 + threadIdx.x;
    float s = 0.f;
    #pragma unroll
    for (int j = 0; j < 8; ++j) s += part[((ll)j * 8 + b) * 2048 + m];
    const float iv = 1.0f / s;
    const __bf16* p = E + (ll)b * 2048 * 2048 + (ll)(lc * 256) * 2048 + m;
    float*  qo = attn    + (ll)b * 2048 * 2048 + (ll)(lc * 256) * 2048 + m;
    __bf16* ro = attn_bf + (ll)b * 2048 * 2048 + (ll)(lc * 256) * 2048 + m;
    #pragma unroll 4
    for (int l = 0; l < 256; ++l) {
        float a = (float)p[(ll)l * 2048] * iv;
        qo[(ll)l * 2048] = a;
        ro[(ll)l * 2048] = (__bf16)a;
    }
}

// ---------------------------------------------------------------------------
extern "C" void kernel_launch(void* const* d_in, const int* in_sizes, int n_in,
                              void* d_out, int out_size, void* d_ws, size_t ws_size,
                              hipStream_t stream)
{
    const float* X   = (const float*)d_in[0];
    const float* Wq  = (const float*)d_in[1];
    const float* bq  = (const float*)d_in[2];
    const float* Wk  = (const float*)d_in[3];
    const float* bk  = (const float*)d_in[4];
    const float* Wv  = (const float*)d_in[5];
    const float* bv  = (const float*)d_in[6];
    const int*   msk = (const int*)d_in[7];

    float* out  = (float*)d_out;                  // (8,2048,1024) fp32
    float* attn = out + (ll)8 * 2048 * 1024;      // (8,2048,2048) fp32

    __bf16* Xb = (__bf16*)attn;                   // staging in attn region
    __bf16* Wb = Xb + (ll)16384 * 1024;
    float*  bb = (float*)(Wb + (ll)3072 * 1024);

    __bf16* qkv = (__bf16*)d_ws;                  // 96 MiB
    __bf16* vt  = qkv + (ll)16384 * 3072;         // 32 MiB

    // 0) bf16 conversions
    cvt_k<<<dim3(8192), 256, 0, stream>>>(X, Xb, 16384 * 1024 / 8);
    cvt_k<<<dim3(512),  256, 0, stream>>>(Wq, Wb,               1024 * 1024 / 8);
    cvt_k<<<dim3(512),  256, 0, stream>>>(Wk, Wb + 1024 * 1024, 1024 * 1024 / 8);
    cvt_k<<<dim3(512),  256, 0, stream>>>(Wv, Wb + 2048 * 1024, 1024 * 1024 / 8);
    cvtb_k<<<dim3(12),  256, 0, stream>>>(bq, bk, bv, bb);

    // 1) QKV projection
    gemm8<0><<<dim3(64, 12, 1), 512, 0, stream>>>(
        Xb, Wb, qkv, bb, msk, nullptr,
        1024, 1024, 1024, 3072, 0LL, 0LL, 0LL);

    const size_t need_fused =
        (size_t)(16384ll*3072 + 8ll*1024*2048 + 8ll*2048*2048) * 2
        + (size_t)(8*8*2048 + 8*2048) * 4;

    if (ws_size >= need_fused) {
        // fused path: E in ws, inv folded into V^T, attn fused into PV
        __bf16* E   = vt + (ll)8 * 1024 * 2048;
        float*  prt = (float*)(E + (ll)8 * 2048 * 2048);
        float*  inv = prt + 8 * 8 * 2048;

        // 2) E = exp(QK^T/32, masked) -> ws; fused column partial sums
        gemm8<1><<<dim3(8, 8, 8), 512, 0, stream>>>(
            qkv, qkv + 1024, E, nullptr, msk, prt,
            1024, 3072, 3072, 2048,
            (ll)2048 * 3072, (ll)2048 * 3072, (ll)2048 * 2048);

        // 3) inv = 1/colsum
        rsum_k<<<dim3(64), 256, 0, stream>>>(prt, inv);

        // 4) vt = (V * inv)^T
        vtp_k<<<dim3(32, 16, 8), 256, 0, stream>>>(qkv, inv, vt);

        // 5) out = E @ vt^T  +  attn = E * inv (fused epilogue)
        pv128<<<dim3(16, 4, 8), 512, 0, stream>>>(E, vt, inv, out, attn, msk);
    } else {
        // fallback: round-4 proven pipeline
        __bf16* E   = (__bf16*)d_out;
        float*  prt = (float*)(vt + (ll)8 * 1024 * 2048);
        __bf16* attn_bf = qkv;

        vt_k<<<dim3(32, 16, 8), 256, 0, stream>>>((const unsigned short*)qkv,
                                                  (unsigned short*)vt);

        gemm8<1><<<dim3(8, 8, 8), 512, 0, stream>>>(
            qkv, qkv + 1024, E, nullptr, msk, nullptr,
            1024, 3072, 3072, 2048,
            (ll)2048 * 3072, (ll)2048 * 3072, (ll)2048 * 2048);

        colsum_k<<<dim3(8, 8, 8), 256, 0, stream>>>(E, prt);
        norm_k<<<dim3(8, 8, 8), 256, 0, stream>>>(E, prt, attn, attn_bf);

        gemm8<2><<<dim3(8, 4, 8), 512, 0, stream>>>(
            attn_bf, vt, out, nullptr, msk, nullptr,
            2048, 2048, 2048, 1024,
            (ll)2048 * 2048, (ll)1024 * 2048, (ll)2048 * 1024);
    }
}